// Round 6
// baseline (1843.552 us; speedup 1.0000x reference)
//
#include <hip/hip_runtime.h>
#include <cstdint>
#include <cstddef>

#define NNODES 50000
#define NEDGES 20000
#define NNZT   1600000
#define CCAT   1024   // 4*256 concat features
#define CIN    256
#define COUT   40

// chunk-grouped adjacency: neighbor lists sorted by 1024-wide chunk of the gathered
// array (2KB/row node-major => 2MB chunk granule, L2-resident per XCD).
#define NCHN 49   // ceil(50000/1024) node chunks
#define NCHE 20   // ceil(20000/1024) edge chunks

typedef __attribute__((ext_vector_type(8))) short bf16x8;
typedef __attribute__((ext_vector_type(4))) float f32x4;

__device__ inline float bflo(unsigned u) { return __uint_as_float(u << 16); }
__device__ inline float bfhi(unsigned u) { return __uint_as_float(u & 0xffff0000u); }
__device__ inline float bfs(unsigned short u) { return __uint_as_float((unsigned)u << 16); }
__device__ inline unsigned short f2bf(float f) {
  unsigned u = __float_as_uint(f);
  u += 0x7fff + ((u >> 16) & 1);
  return (unsigned short)(u >> 16);
}
__device__ inline unsigned packbf(float a, float b) {
  return (unsigned)f2bf(a) | ((unsigned)f2bf(b) << 16);
}

// ---------------- CSR build (chunk-grouped) ----------------

__global__ void count_k(const int* __restrict__ ni, const int* __restrict__ ei,
                        int* __restrict__ cnt_ec, int* __restrict__ cnt_nc) {
  int i = blockIdx.x * 256 + threadIdx.x;
  if (i < NNZT) {
    int n = ni[i], e = ei[i];
    atomicAdd(&cnt_ec[e * NCHN + (n >> 10)], 1);
    atomicAdd(&cnt_nc[n * NCHE + (e >> 10)], 1);
  }
}

// ---- hierarchical exclusive scan (3 kernels; len up to 1024*1024) ----

__global__ __launch_bounds__(256) void scan_sum_k(
    const int* __restrict__ cnt, int* __restrict__ blksum, int len) {
  int b = blockIdx.x;
  int i0 = b * 1024 + threadIdx.x * 4;
  int s = 0;
  #pragma unroll
  for (int j = 0; j < 4; j++) { int i = i0 + j; if (i < len) s += cnt[i]; }
  __shared__ int sh[4];
  for (int d = 32; d > 0; d >>= 1) s += __shfl_down(s, d);
  if ((threadIdx.x & 63) == 0) sh[threadIdx.x >> 6] = s;
  __syncthreads();
  if (threadIdx.x == 0) blksum[b] = sh[0] + sh[1] + sh[2] + sh[3];
}

__global__ __launch_bounds__(1024) void scan_top_k(int* __restrict__ blksum, int nblk) {
  // in-place exclusive scan of blksum[0..nblk), nblk <= 1024
  __shared__ int sh[1024];
  int t = threadIdx.x;
  int v = (t < nblk) ? blksum[t] : 0;
  sh[t] = v;
  __syncthreads();
  for (int d = 1; d < 1024; d <<= 1) {
    int u = (t >= d) ? sh[t - d] : 0;
    __syncthreads();
    sh[t] += u;
    __syncthreads();
  }
  if (t < nblk) blksum[t] = sh[t] - v;
}

__global__ __launch_bounds__(256) void scan_apply_k(
    const int* __restrict__ cnt, const int* __restrict__ blksum,
    int* __restrict__ off, int len) {
  int b = blockIdx.x;
  int t = threadIdx.x;
  int i0 = b * 1024 + t * 4;
  int v[4];
  int s = 0;
  #pragma unroll
  for (int j = 0; j < 4; j++) { int i = i0 + j; v[j] = (i < len) ? cnt[i] : 0; s += v[j]; }
  __shared__ int sh[256];
  sh[t] = s;
  __syncthreads();
  for (int d = 1; d < 256; d <<= 1) {
    int u = (t >= d) ? sh[t - d] : 0;
    __syncthreads();
    sh[t] += u;
    __syncthreads();
  }
  int run = blksum[b] + sh[t] - s;   // exclusive prefix at this thread's first elem
  #pragma unroll
  for (int j = 0; j < 4; j++) {
    int i = i0 + j;
    if (i < len) off[i] = run;
    run += v[j];
  }
  if (b == gridDim.x - 1 && t == 255) off[len] = run;  // grand total
}

__global__ void fill_k(const int* __restrict__ ni, const int* __restrict__ ei,
                       const int* __restrict__ off_ec, const int* __restrict__ off_nc,
                       int* __restrict__ cur_ec, int* __restrict__ cur_nc,
                       int* __restrict__ adj_e, int* __restrict__ adj_n) {
  int i = blockIdx.x * 256 + threadIdx.x;
  if (i < NNZT) {
    int e = ei[i], n = ni[i];
    int ce = e * NCHN + (n >> 10);
    int p = atomicAdd(&cur_ec[ce], 1);
    adj_e[off_ec[ce] + p] = n;
    int cn = n * NCHE + (e >> 10);
    int q = atomicAdd(&cur_nc[cn], 1);
    adj_n[off_nc[cn] + q] = e;
  }
}

__global__ void deg_k(const int* __restrict__ off_ec, const int* __restrict__ off_nc,
                      float* __restrict__ de_inv, float* __restrict__ dv_is) {
  int i = blockIdx.x * 256 + threadIdx.x;
  if (i < NNODES) {
    int d = off_nc[(i + 1) * NCHE] - off_nc[i * NCHE];
    dv_is[i] = (d > 0) ? rsqrtf((float)d) : 0.f;
  }
  if (i < NEDGES) {
    int d = off_ec[(i + 1) * NCHN] - off_ec[i * NCHN];
    de_inv[i] = (d > 0) ? (1.f / (float)d) : 0.f;
  }
}

// ---------------- s1 = S * ones (bias-through-smooth) ----------------

__global__ void t1_k(const int* __restrict__ off_ec, const int* __restrict__ adj_e,
                     const float* __restrict__ dv_is, const float* __restrict__ de_inv,
                     float* __restrict__ t1) {
  int e = blockIdx.x; int lane = threadIdx.x;
  int beg = off_ec[e * NCHN], end = off_ec[e * NCHN + NCHN];
  float s = 0.f;
  for (int j = beg + lane; j < end; j += 64) s += dv_is[adj_e[j]];
  for (int d = 32; d > 0; d >>= 1) s += __shfl_down(s, d);
  if (lane == 0) t1[e] = s * de_inv[e];
}

__global__ void s1_k(const int* __restrict__ off_nc, const int* __restrict__ adj_n,
                     const float* __restrict__ t1, const float* __restrict__ dv_is,
                     float* __restrict__ s1) {
  int n = blockIdx.x; int lane = threadIdx.x;
  int beg = off_nc[n * NCHE], end = off_nc[n * NCHE + NCHE];
  float s = 0.f;
  for (int j = beg + lane; j < end; j += 64) s += t1[adj_n[j]];
  for (int d = 32; d > 0; d >>= 1) s += __shfl_down(s, d);
  if (lane == 0) s1[n] = s * dv_is[n];
}

// ------- castx: xq[n][br*256+c] = bf16(dv_is[n]*x[br][n][c]); row NNODES = zeros ----

__global__ __launch_bounds__(256) void castx_k(
    const float* __restrict__ x, const float* __restrict__ dv_is,
    unsigned short* __restrict__ xq) {
  int n = blockIdx.x;
  int t = threadIdx.x;
  int br = t >> 6, c4 = (t & 63) * 4;
  unsigned short* op = xq + (size_t)n * CCAT + br * 256 + c4;
  if (n == NNODES) {   // dummy sentinel row
    ushort4 z = {0, 0, 0, 0};
    *(ushort4*)op = z;
    return;
  }
  float dv = dv_is[n];
  float4 v = *(const float4*)(x + ((size_t)br * NNODES + n) * CIN + c4);
  ushort4 o;
  o.x = f2bf(v.x * dv); o.y = f2bf(v.y * dv);
  o.z = f2bf(v.z * dv); o.w = f2bf(v.w * dv);
  *(ushort4*)op = o;
}

// W1t[br][n][k] = bf16(W1[br][k][n])
__global__ __launch_bounds__(256) void castw1_k(
    const float* __restrict__ W1, unsigned short* __restrict__ W1t) {
  int n = blockIdx.x, br = blockIdx.y, t = threadIdx.x;
  float v = W1[((size_t)br * CIN + t) * CIN + n];
  W1t[((size_t)br * CIN + n) * CIN + t] = f2bf(v);
}

// zero the sentinel row G[NEDGES][0..1023]
__global__ __launch_bounds__(256) void zerog_k(unsigned short* __restrict__ G) {
  ushort4 z = {0, 0, 0, 0};
  *(ushort4*)(G + (size_t)NEDGES * CCAT + threadIdx.x * 4) = z;
}

// ------- edge gather, branch-fused node-major: one wave per edge, all 4 branches ----
// ef[e][br*256+c] = de_inv[e] * sum_{n in e} xq[n][br*256+c]

__global__ __launch_bounds__(256) void gatherx_k(
    const unsigned short* __restrict__ xq, const int* __restrict__ off_ec,
    const int* __restrict__ adj_e, const float* __restrict__ de_inv,
    unsigned short* __restrict__ ef) {
  int e = blockIdx.x * 4 + (threadIdx.x >> 6);
  int lane = threadIdx.x & 63;
  const unsigned short* base = xq + lane * 4;
  int beg = off_ec[e * NCHN], end = off_ec[e * NCHN + NCHN];
  float4 A0 = {0, 0, 0, 0}, A1 = {0, 0, 0, 0}, A2 = {0, 0, 0, 0}, A3 = {0, 0, 0, 0};
  int n0 = (beg < end) ? adj_e[beg] : NNODES;
  int n1 = (beg + 1 < end) ? adj_e[beg + 1] : NNODES;
  for (int j = beg; j < end; j += 2) {
    int c0 = n0, c1 = n1;
    n0 = (j + 2 < end) ? adj_e[j + 2] : NNODES;
    n1 = (j + 3 < end) ? adj_e[j + 3] : NNODES;
    const unsigned short* p0 = base + (size_t)c0 * CCAT;
    const unsigned short* p1 = base + (size_t)c1 * CCAT;
    uint2 u0 = *(const uint2*)(p0);
    uint2 u1 = *(const uint2*)(p0 + 256);
    uint2 u2 = *(const uint2*)(p0 + 512);
    uint2 u3 = *(const uint2*)(p0 + 768);
    uint2 w0 = *(const uint2*)(p1);
    uint2 w1 = *(const uint2*)(p1 + 256);
    uint2 w2 = *(const uint2*)(p1 + 512);
    uint2 w3 = *(const uint2*)(p1 + 768);
    A0.x += bflo(u0.x) + bflo(w0.x); A0.y += bfhi(u0.x) + bfhi(w0.x);
    A0.z += bflo(u0.y) + bflo(w0.y); A0.w += bfhi(u0.y) + bfhi(w0.y);
    A1.x += bflo(u1.x) + bflo(w1.x); A1.y += bfhi(u1.x) + bfhi(w1.x);
    A1.z += bflo(u1.y) + bflo(w1.y); A1.w += bfhi(u1.y) + bfhi(w1.y);
    A2.x += bflo(u2.x) + bflo(w2.x); A2.y += bfhi(u2.x) + bfhi(w2.x);
    A2.z += bflo(u2.y) + bflo(w2.y); A2.w += bfhi(u2.y) + bfhi(w2.y);
    A3.x += bflo(u3.x) + bflo(w3.x); A3.y += bfhi(u3.x) + bfhi(w3.x);
    A3.z += bflo(u3.y) + bflo(w3.y); A3.w += bfhi(u3.y) + bfhi(w3.y);
  }
  float sc = de_inv[e];
  unsigned short* op = ef + (size_t)e * CCAT + lane * 4;
  uint2 o;
  o.x = packbf(A0.x * sc, A0.y * sc); o.y = packbf(A0.z * sc, A0.w * sc);
  *(uint2*)(op) = o;
  o.x = packbf(A1.x * sc, A1.y * sc); o.y = packbf(A1.z * sc, A1.w * sc);
  *(uint2*)(op + 256) = o;
  o.x = packbf(A2.x * sc, A2.y * sc); o.y = packbf(A2.z * sc, A2.w * sc);
  *(uint2*)(op + 512) = o;
  o.x = packbf(A3.x * sc, A3.y * sc); o.y = packbf(A3.z * sc, A3.w * sc);
  *(uint2*)(op + 768) = o;
}

// ---------------- GEMM1 (MFMA bf16): G[e][br*256+f] = ef[e][br] @ W1[br] --------

__global__ __launch_bounds__(256) void gemm1_k(
    const unsigned short* __restrict__ ef,   // [E][1024] bf16 row-major
    const unsigned short* __restrict__ W1t,  // [4][256(n)][256(k)] bf16
    unsigned short* __restrict__ G) {        // [E+1][1024] bf16 concat-major
  int rb = blockIdx.x, cb = blockIdx.y, br = blockIdx.z;
  int t = threadIdx.x;
  int w = t >> 6, l = t & 63;
  __shared__ unsigned short As[64 * 40];
  __shared__ unsigned short Bs[64 * 40];
  f32x4 acc[4] = {};
  int row0 = rb * 64;
  int srow = t >> 2, seg = t & 3;
  bool aok = (row0 + srow) < NEDGES;
  const unsigned short* ap = ef + (size_t)(row0 + srow) * CCAT + br * 256 + seg * 8;
  const unsigned short* bp = W1t + ((size_t)br * CIN + cb * 64 + srow) * CIN + seg * 8;
  int m = l & 15, q = l >> 4;
  for (int k0 = 0; k0 < CIN; k0 += 32) {
    uint4 av = {0, 0, 0, 0};
    if (aok) av = *(const uint4*)(ap + k0);
    uint4 bv = *(const uint4*)(bp + k0);
    *(uint4*)&As[srow * 40 + seg * 8] = av;
    *(uint4*)&Bs[srow * 40 + seg * 8] = bv;
    __syncthreads();
    bf16x8 a = *(bf16x8*)&As[(w * 16 + m) * 40 + q * 8];
    #pragma unroll
    for (int c = 0; c < 4; c++) {
      bf16x8 b = *(bf16x8*)&Bs[(c * 16 + m) * 40 + q * 8];
      acc[c] = __builtin_amdgcn_mfma_f32_16x16x32_bf16(a, b, acc[c], 0, 0, 0);
    }
    __syncthreads();
  }
  #pragma unroll
  for (int c = 0; c < 4; c++) {
    int f = cb * 64 + c * 16 + m;   // within-branch channel
    #pragma unroll
    for (int r = 0; r < 4; r++) {
      int row = row0 + w * 16 + q * 4 + r;
      if (row < NEDGES)
        G[(size_t)row * CCAT + br * 256 + f] = f2bf(acc[c][r]);
    }
  }
}

// ------- node scatter + bias + relu, branch-fused: one wave per node ----------

__global__ __launch_bounds__(256) void scatter_h_k(
    const unsigned short* __restrict__ G, const int* __restrict__ off_nc,
    const int* __restrict__ adj_n, const float* __restrict__ dv_is,
    const float* __restrict__ s1, const float* __restrict__ b1,
    unsigned short* __restrict__ hid) {   // [N][1024] concat-major
  int n = blockIdx.x * 4 + (threadIdx.x >> 6);
  int lane = threadIdx.x & 63;
  const unsigned short* base = G + lane * 4;
  int beg = off_nc[n * NCHE], end = off_nc[n * NCHE + NCHE];
  float4 A0 = {0, 0, 0, 0}, A1 = {0, 0, 0, 0}, A2 = {0, 0, 0, 0}, A3 = {0, 0, 0, 0};
  int n0 = (beg < end) ? adj_n[beg] : NEDGES;
  int n1 = (beg + 1 < end) ? adj_n[beg + 1] : NEDGES;
  for (int j = beg; j < end; j += 2) {
    int c0 = n0, c1 = n1;
    n0 = (j + 2 < end) ? adj_n[j + 2] : NEDGES;
    n1 = (j + 3 < end) ? adj_n[j + 3] : NEDGES;
    const unsigned short* p0 = base + (size_t)c0 * CCAT;
    const unsigned short* p1 = base + (size_t)c1 * CCAT;
    uint2 u0 = *(const uint2*)(p0);
    uint2 u1 = *(const uint2*)(p0 + 256);
    uint2 u2 = *(const uint2*)(p0 + 512);
    uint2 u3 = *(const uint2*)(p0 + 768);
    uint2 w0 = *(const uint2*)(p1);
    uint2 w1 = *(const uint2*)(p1 + 256);
    uint2 w2 = *(const uint2*)(p1 + 512);
    uint2 w3 = *(const uint2*)(p1 + 768);
    A0.x += bflo(u0.x) + bflo(w0.x); A0.y += bfhi(u0.x) + bfhi(w0.x);
    A0.z += bflo(u0.y) + bflo(w0.y); A0.w += bfhi(u0.y) + bfhi(w0.y);
    A1.x += bflo(u1.x) + bflo(w1.x); A1.y += bfhi(u1.x) + bfhi(w1.x);
    A1.z += bflo(u1.y) + bflo(w1.y); A1.w += bfhi(u1.y) + bfhi(w1.y);
    A2.x += bflo(u2.x) + bflo(w2.x); A2.y += bfhi(u2.x) + bfhi(w2.x);
    A2.z += bflo(u2.y) + bflo(w2.y); A2.w += bfhi(u2.y) + bfhi(w2.y);
    A3.x += bflo(u3.x) + bflo(w3.x); A3.y += bfhi(u3.x) + bfhi(w3.x);
    A3.z += bflo(u3.y) + bflo(w3.y); A3.w += bfhi(u3.y) + bfhi(w3.y);
  }
  float wv = dv_is[n], sb = s1[n];
  const float* bp = b1 + lane * 4;
  float4 B0 = *(const float4*)(bp);
  float4 B1 = *(const float4*)(bp + 256);
  float4 B2 = *(const float4*)(bp + 512);
  float4 B3 = *(const float4*)(bp + 768);
  unsigned short* op = hid + (size_t)n * CCAT + lane * 4;
  uint2 o;
  o.x = packbf(fmaxf(wv * A0.x + sb * B0.x, 0.f), fmaxf(wv * A0.y + sb * B0.y, 0.f));
  o.y = packbf(fmaxf(wv * A0.z + sb * B0.z, 0.f), fmaxf(wv * A0.w + sb * B0.w, 0.f));
  *(uint2*)(op) = o;
  o.x = packbf(fmaxf(wv * A1.x + sb * B1.x, 0.f), fmaxf(wv * A1.y + sb * B1.y, 0.f));
  o.y = packbf(fmaxf(wv * A1.z + sb * B1.z, 0.f), fmaxf(wv * A1.w + sb * B1.w, 0.f));
  *(uint2*)(op + 256) = o;
  o.x = packbf(fmaxf(wv * A2.x + sb * B2.x, 0.f), fmaxf(wv * A2.y + sb * B2.y, 0.f));
  o.y = packbf(fmaxf(wv * A2.z + sb * B2.z, 0.f), fmaxf(wv * A2.w + sb * B2.w, 0.f));
  *(uint2*)(op + 512) = o;
  o.x = packbf(fmaxf(wv * A3.x + sb * B3.x, 0.f), fmaxf(wv * A3.y + sb * B3.y, 0.f));
  o.y = packbf(fmaxf(wv * A3.z + sb * B3.z, 0.f), fmaxf(wv * A3.w + sb * B3.w, 0.f));
  *(uint2*)(op + 768) = o;
}

// ---------------- GEMM2: u = hidden @ W2 + b2 (hidden [N][1024], U bf16) ----

__global__ __launch_bounds__(256) void gemm2_k(
    const unsigned short* __restrict__ H, const float* __restrict__ W2,
    const float* __restrict__ b2, unsigned short* __restrict__ U) {
  int nb = blockIdx.x;
  int t = threadIdx.x;
  int r = t & 127, ch = t >> 7;
  __shared__ float Hs[64][257];
  __shared__ float Ws[64][40];
  float acc0[20] = {}, acc1[20] = {};
  int n0 = nb * 256;
  for (int k0 = 0; k0 < CCAT; k0 += 64) {
    #pragma unroll
    for (int i = 0; i < 8; i++) {
      int li = i * 256 + t;
      int row = li >> 3, kv = li & 7;
      uint4 v = {0, 0, 0, 0};
      int n = n0 + row;
      if (n < NNODES) v = *(const uint4*)(H + (size_t)n * CCAT + k0 + kv * 8);
      int kb = kv * 8;
      Hs[kb + 0][row] = bflo(v.x); Hs[kb + 1][row] = bfhi(v.x);
      Hs[kb + 2][row] = bflo(v.y); Hs[kb + 3][row] = bfhi(v.y);
      Hs[kb + 4][row] = bflo(v.z); Hs[kb + 5][row] = bfhi(v.z);
      Hs[kb + 6][row] = bflo(v.w); Hs[kb + 7][row] = bfhi(v.w);
    }
    #pragma unroll
    for (int i = 0; i < 10; i++) {
      int li = i * 256 + t;
      int k = li / 40, o2 = li - k * 40;
      Ws[k][o2] = W2[(size_t)(k0 + k) * COUT + o2];
    }
    __syncthreads();
    #pragma unroll 4
    for (int k = 0; k < 64; k++) {
      float h0 = Hs[k][r];
      float h1 = Hs[k][r + 128];
      const float* wr = &Ws[k][ch * 20];
      #pragma unroll
      for (int i = 0; i < 5; i++) {
        float4 wv = *(const float4*)(wr + i * 4);
        acc0[i * 4 + 0] += h0 * wv.x; acc0[i * 4 + 1] += h0 * wv.y;
        acc0[i * 4 + 2] += h0 * wv.z; acc0[i * 4 + 3] += h0 * wv.w;
        acc1[i * 4 + 0] += h1 * wv.x; acc1[i * 4 + 1] += h1 * wv.y;
        acc1[i * 4 + 2] += h1 * wv.z; acc1[i * 4 + 3] += h1 * wv.w;
      }
    }
    __syncthreads();
  }
  int n_a = n0 + r, n_b = n0 + r + 128;
  if (n_a < NNODES) {
    #pragma unroll
    for (int j = 0; j < 20; j++) {
      int o2 = ch * 20 + j;
      U[(size_t)n_a * COUT + o2] = f2bf(acc0[j] + b2[o2]);
    }
  }
  if (n_b < NNODES) {
    #pragma unroll
    for (int j = 0; j < 20; j++) {
      int o2 = ch * 20 + j;
      U[(size_t)n_b * COUT + o2] = f2bf(acc1[j] + b2[o2]);
    }
  }
}

// ---------------- final smooth (40 channels; U bf16, 4MB table) ----------------

__global__ __launch_bounds__(256) void gather_u_k(
    const unsigned short* __restrict__ U, const int* __restrict__ off_ec,
    const int* __restrict__ adj_e, const float* __restrict__ dv_is,
    const float* __restrict__ de_inv, float* __restrict__ ef2) {
  int e = blockIdx.x;
  int t = threadIdx.x;
  int w = t >> 6, lane = t & 63;
  __shared__ float red[4][COUT];
  float acc = 0.f;
  int beg = off_ec[e * NCHN], end = off_ec[e * NCHN + NCHN];
  if (lane < COUT) {
    for (int j = beg + w; j < end; j += 4) {
      int n = adj_e[j];
      acc += dv_is[n] * bfs(U[(size_t)n * COUT + lane]);
    }
    red[w][lane] = acc;
  }
  __syncthreads();
  if (t < COUT) {
    float s = red[0][t] + red[1][t] + red[2][t] + red[3][t];
    ef2[(size_t)e * COUT + t] = s * de_inv[e];
  }
}

__global__ __launch_bounds__(256) void scatter_out_k(
    const float* __restrict__ ef2, const int* __restrict__ off_nc,
    const int* __restrict__ adj_n, const float* __restrict__ dv_is,
    float* __restrict__ out) {
  int n = blockIdx.x;
  int t = threadIdx.x;
  int w = t >> 6, lane = t & 63;
  __shared__ float red[4][COUT];
  float acc = 0.f;
  int beg = off_nc[n * NCHE], end = off_nc[n * NCHE + NCHE];
  if (lane < COUT) {
    for (int j = beg + w; j < end; j += 4) {
      acc += ef2[(size_t)adj_n[j] * COUT + lane];
    }
    red[w][lane] = acc;
  }
  __syncthreads();
  if (t < COUT) {
    out[(size_t)n * COUT + t] = dv_is[n] * (red[0][t] + red[1][t] + red[2][t] + red[3][t]);
  }
}

// ---------------- launch ----------------

extern "C" void kernel_launch(void* const* d_in, const int* in_sizes, int n_in,
                              void* d_out, int out_size, void* d_ws, size_t ws_size,
                              hipStream_t stream) {
  const float* x  = (const float*)d_in[0];
  const float* W1 = (const float*)d_in[1];
  const float* b1 = (const float*)d_in[2];
  const float* W2 = (const float*)d_in[3];
  const float* b2 = (const float*)d_in[4];
  const int* ni   = (const int*)d_in[5];
  const int* ei   = (const int*)d_in[6];
  float* out = (float*)d_out;

  char* ws = (char*)d_ws;
  size_t o = 0;
  int* off_ec = (int*)(ws + o); o += (size_t)(NEDGES * NCHN + 1) * 4; o = (o + 255) & ~(size_t)255;
  int* off_nc = (int*)(ws + o); o += (size_t)(NNODES * NCHE + 1) * 4; o = (o + 255) & ~(size_t)255;
  float* de_inv = (float*)(ws + o); o += (size_t)NEDGES * 4;
  float* dv_is  = (float*)(ws + o); o += (size_t)NNODES * 4;
  float* t1     = (float*)(ws + o); o += (size_t)NEDGES * 4;
  float* s1     = (float*)(ws + o); o += (size_t)NNODES * 4; o = (o + 255) & ~(size_t)255;
  int* adj_e = (int*)(ws + o); o += (size_t)NNZT * 4;
  int* adj_n = (int*)(ws + o); o += (size_t)NNZT * 4; o = (o + 255) & ~(size_t)255;
  unsigned short* W1t = (unsigned short*)(ws + o); o += (size_t)4 * CIN * CIN * 2; o = (o + 255) & ~(size_t)255;
  // regionA: xq [(N+1)][1024] bf16 node-major (+sentinel row); reused as hidden [N][1024]
  unsigned short* xq     = (unsigned short*)(ws + o);
  unsigned short* hidden = xq;
  o += (size_t)(NNODES + 1) * CCAT * 2; o = (o + 255) & ~(size_t)255;
  // regionB: ef [E][1024] bf16 row-major; later U [N][40] bf16 + ef2 [E][40] f32
  unsigned short* ef = (unsigned short*)(ws + o);
  unsigned short* u  = ef;
  float* ef2 = (float*)((char*)ef + (((size_t)NNODES * COUT * 2 + 255) & ~(size_t)255));
  o += (size_t)NEDGES * CCAT * 2; o = (o + 255) & ~(size_t)255;
  // regionC: G [(E+1)][1024] bf16 concat-major (+sentinel row). The CSR-build
  // cnt/cur/blksum scratch is overlaid at its start (build completes before gemm1
  // writes G; sentinel row at +40.96MB is beyond the ~16MB scratch).
  unsigned short* g = (unsigned short*)(ws + o);
  o += (size_t)(NEDGES + 1) * CCAT * 2;

  int* cnt_ec = (int*)g;                        // [E*NCHN]
  int* cur_ec = cnt_ec + (size_t)NEDGES * NCHN; // [E*NCHN]
  int* cnt_nc = cur_ec + (size_t)NEDGES * NCHN; // [N*NCHE]
  int* cur_nc = cnt_nc + (size_t)NNODES * NCHE; // [N*NCHE]
  int* blk_e  = cur_nc + (size_t)NNODES * NCHE; // [1024]
  int* blk_n  = blk_e + 1024;                   // [1024]

  const int LEN_E = NEDGES * NCHN;              // 980000
  const int LEN_N = NNODES * NCHE;              // 1000000
  const int NBLK_E = (LEN_E + 1023) / 1024;     // 958
  const int NBLK_N = (LEN_N + 1023) / 1024;     // 977

  hipMemsetAsync(cnt_ec, 0,
                 ((size_t)LEN_E + (size_t)LEN_N) * 2 * sizeof(int),
                 stream);
  count_k<<<(NNZT + 255) / 256, 256, 0, stream>>>(ni, ei, cnt_ec, cnt_nc);
  scan_sum_k<<<NBLK_E, 256, 0, stream>>>(cnt_ec, blk_e, LEN_E);
  scan_top_k<<<1, 1024, 0, stream>>>(blk_e, NBLK_E);
  scan_apply_k<<<NBLK_E, 256, 0, stream>>>(cnt_ec, blk_e, off_ec, LEN_E);
  scan_sum_k<<<NBLK_N, 256, 0, stream>>>(cnt_nc, blk_n, LEN_N);
  scan_top_k<<<1, 1024, 0, stream>>>(blk_n, NBLK_N);
  scan_apply_k<<<NBLK_N, 256, 0, stream>>>(cnt_nc, blk_n, off_nc, LEN_N);
  fill_k<<<(NNZT + 255) / 256, 256, 0, stream>>>(ni, ei, off_ec, off_nc, cur_ec, cur_nc, adj_e, adj_n);
  deg_k<<<(NNODES + 255) / 256, 256, 0, stream>>>(off_ec, off_nc, de_inv, dv_is);
  castx_k<<<NNODES + 1, 256, 0, stream>>>(x, dv_is, xq);
  castw1_k<<<dim3(CIN, 4), 256, 0, stream>>>(W1, W1t);
  zerog_k<<<1, 256, 0, stream>>>(g);
  t1_k<<<NEDGES, 64, 0, stream>>>(off_ec, adj_e, dv_is, de_inv, t1);
  s1_k<<<NNODES, 64, 0, stream>>>(off_nc, adj_n, t1, dv_is, s1);
  gatherx_k<<<NEDGES / 4, 256, 0, stream>>>(xq, off_ec, adj_e, de_inv, ef);
  gemm1_k<<<dim3((NEDGES + 63) / 64, 4, 4), 256, 0, stream>>>(ef, W1t, g);
  scatter_h_k<<<NNODES / 4, 256, 0, stream>>>(g, off_nc, adj_n, dv_is, s1, b1, hidden);
  gemm2_k<<<(NNODES + 255) / 256, 256, 0, stream>>>(hidden, W2, b2, u);
  gather_u_k<<<NEDGES, 256, 0, stream>>>(u, off_ec, adj_e, dv_is, de_inv, ef2);
  scatter_out_k<<<NNODES, 256, 0, stream>>>(ef2, off_nc, adj_n, dv_is, out);
}

// Round 7
// 1643.891 us; speedup vs baseline: 1.1215x; 1.1215x over previous
//
#include <hip/hip_runtime.h>
#include <cstdint>
#include <cstddef>

#define NNODES 50000
#define NEDGES 20000
#define NNZT   1600000
#define CCAT   1024   // 4*256 concat features
#define CIN    256
#define COUT   40

// chunk-grouped adjacency: neighbor lists sorted by 4096-wide chunk of the gathered
// array (passive cross-block temporal locality; R5 measured 1.30GB beyond-L2 vs
// 1.51GB unsorted). Branch-major slabs; branch phases serialized by dispatch order.
#define NCHN 13   // ceil(50000/4096) node chunks
#define NCHE 5    // ceil(20000/4096) edge chunks

typedef __attribute__((ext_vector_type(8))) short bf16x8;
typedef __attribute__((ext_vector_type(4))) float f32x4;

__device__ inline float bflo(unsigned u) { return __uint_as_float(u << 16); }
__device__ inline float bfhi(unsigned u) { return __uint_as_float(u & 0xffff0000u); }
__device__ inline float bfs(unsigned short u) { return __uint_as_float((unsigned)u << 16); }
__device__ inline unsigned short f2bf(float f) {
  unsigned u = __float_as_uint(f);
  u += 0x7fff + ((u >> 16) & 1);
  return (unsigned short)(u >> 16);
}
__device__ inline unsigned packbf(float a, float b) {
  return (unsigned)f2bf(a) | ((unsigned)f2bf(b) << 16);
}

// ---------------- CSR build (chunk-grouped) ----------------

__global__ void count_k(const int* __restrict__ ni, const int* __restrict__ ei,
                        int* __restrict__ cnt_ec, int* __restrict__ cnt_nc) {
  int i = blockIdx.x * 256 + threadIdx.x;
  if (i < NNZT) {
    int n = ni[i], e = ei[i];
    atomicAdd(&cnt_ec[e * NCHN + (n >> 12)], 1);
    atomicAdd(&cnt_nc[n * NCHE + (e >> 12)], 1);
  }
}

// ---- hierarchical exclusive scan (3 kernels; len up to 1024*1024) ----

__global__ __launch_bounds__(256) void scan_sum_k(
    const int* __restrict__ cnt, int* __restrict__ blksum, int len) {
  int b = blockIdx.x;
  int i0 = b * 1024 + threadIdx.x * 4;
  int s = 0;
  #pragma unroll
  for (int j = 0; j < 4; j++) { int i = i0 + j; if (i < len) s += cnt[i]; }
  __shared__ int sh[4];
  for (int d = 32; d > 0; d >>= 1) s += __shfl_down(s, d);
  if ((threadIdx.x & 63) == 0) sh[threadIdx.x >> 6] = s;
  __syncthreads();
  if (threadIdx.x == 0) blksum[b] = sh[0] + sh[1] + sh[2] + sh[3];
}

__global__ __launch_bounds__(1024) void scan_top_k(int* __restrict__ blksum, int nblk) {
  // in-place exclusive scan of blksum[0..nblk), nblk <= 1024
  __shared__ int sh[1024];
  int t = threadIdx.x;
  int v = (t < nblk) ? blksum[t] : 0;
  sh[t] = v;
  __syncthreads();
  for (int d = 1; d < 1024; d <<= 1) {
    int u = (t >= d) ? sh[t - d] : 0;
    __syncthreads();
    sh[t] += u;
    __syncthreads();
  }
  if (t < nblk) blksum[t] = sh[t] - v;
}

__global__ __launch_bounds__(256) void scan_apply_k(
    const int* __restrict__ cnt, const int* __restrict__ blksum,
    int* __restrict__ off, int len) {
  int b = blockIdx.x;
  int t = threadIdx.x;
  int i0 = b * 1024 + t * 4;
  int v[4];
  int s = 0;
  #pragma unroll
  for (int j = 0; j < 4; j++) { int i = i0 + j; v[j] = (i < len) ? cnt[i] : 0; s += v[j]; }
  __shared__ int sh[256];
  sh[t] = s;
  __syncthreads();
  for (int d = 1; d < 256; d <<= 1) {
    int u = (t >= d) ? sh[t - d] : 0;
    __syncthreads();
    sh[t] += u;
    __syncthreads();
  }
  int run = blksum[b] + sh[t] - s;   // exclusive prefix at this thread's first elem
  #pragma unroll
  for (int j = 0; j < 4; j++) {
    int i = i0 + j;
    if (i < len) off[i] = run;
    run += v[j];
  }
  if (b == gridDim.x - 1 && t == 255) off[len] = run;  // grand total
}

__global__ void fill_k(const int* __restrict__ ni, const int* __restrict__ ei,
                       const int* __restrict__ off_ec, const int* __restrict__ off_nc,
                       int* __restrict__ cur_ec, int* __restrict__ cur_nc,
                       int* __restrict__ adj_e, int* __restrict__ adj_n) {
  int i = blockIdx.x * 256 + threadIdx.x;
  if (i < NNZT) {
    int e = ei[i], n = ni[i];
    int ce = e * NCHN + (n >> 12);
    int p = atomicAdd(&cur_ec[ce], 1);
    adj_e[off_ec[ce] + p] = n;
    int cn = n * NCHE + (e >> 12);
    int q = atomicAdd(&cur_nc[cn], 1);
    adj_n[off_nc[cn] + q] = e;
  }
}

__global__ void deg_k(const int* __restrict__ off_ec, const int* __restrict__ off_nc,
                      float* __restrict__ de_inv, float* __restrict__ dv_is) {
  int i = blockIdx.x * 256 + threadIdx.x;
  if (i < NNODES) {
    int d = off_nc[(i + 1) * NCHE] - off_nc[i * NCHE];
    dv_is[i] = (d > 0) ? rsqrtf((float)d) : 0.f;
  }
  if (i < NEDGES) {
    int d = off_ec[(i + 1) * NCHN] - off_ec[i * NCHN];
    de_inv[i] = (d > 0) ? (1.f / (float)d) : 0.f;
  }
}

// ---------------- s1 = S * ones (bias-through-smooth) ----------------

__global__ void t1_k(const int* __restrict__ off_ec, const int* __restrict__ adj_e,
                     const float* __restrict__ dv_is, const float* __restrict__ de_inv,
                     float* __restrict__ t1) {
  int e = blockIdx.x; int lane = threadIdx.x;
  int beg = off_ec[e * NCHN], end = off_ec[e * NCHN + NCHN];
  float s = 0.f;
  for (int j = beg + lane; j < end; j += 64) s += dv_is[adj_e[j]];
  for (int d = 32; d > 0; d >>= 1) s += __shfl_down(s, d);
  if (lane == 0) t1[e] = s * de_inv[e];
}

__global__ void s1_k(const int* __restrict__ off_nc, const int* __restrict__ adj_n,
                     const float* __restrict__ t1, const float* __restrict__ dv_is,
                     float* __restrict__ s1) {
  int n = blockIdx.x; int lane = threadIdx.x;
  int beg = off_nc[n * NCHE], end = off_nc[n * NCHE + NCHE];
  float s = 0.f;
  for (int j = beg + lane; j < end; j += 64) s += t1[adj_n[j]];
  for (int d = 32; d > 0; d >>= 1) s += __shfl_down(s, d);
  if (lane == 0) s1[n] = s * dv_is[n];
}

// ---------------- castx: xq[br][n][256] = bf16(dv_is[n]*x[br][n][:]) ----------------

__global__ __launch_bounds__(256) void castx_k(
    const float* __restrict__ x, const float* __restrict__ dv_is,
    unsigned short* __restrict__ xq) {
  int n = blockIdx.x;
  int t = threadIdx.x;
  int br = t >> 6, c4 = (t & 63) * 4;
  float dv = dv_is[n];
  float4 v = *(const float4*)(x + ((size_t)br * NNODES + n) * CIN + c4);
  ushort4 o;
  o.x = f2bf(v.x * dv); o.y = f2bf(v.y * dv);
  o.z = f2bf(v.z * dv); o.w = f2bf(v.w * dv);
  *(ushort4*)(xq + ((size_t)br * NNODES + n) * CIN + c4) = o;
}

// W1t[br][n][k] = bf16(W1[br][k][n])
__global__ __launch_bounds__(256) void castw1_k(
    const float* __restrict__ W1, unsigned short* __restrict__ W1t) {
  int n = blockIdx.x, br = blockIdx.y, t = threadIdx.x;
  float v = W1[((size_t)br * CIN + t) * CIN + n];
  W1t[((size_t)br * CIN + n) * CIN + t] = f2bf(v);
}

// W2b[p][c][k]: 2-term bf16 split of W2[k][c] (p=0 hi, p=1 residual), cols padded to 48
__global__ __launch_bounds__(256) void castw2_k(
    const float* __restrict__ W2, unsigned short* __restrict__ W2b) {
  int c = blockIdx.x;      // 0..47
  int p = blockIdx.y;      // 0..1
  int t = threadIdx.x;
  for (int k0 = 0; k0 < CCAT; k0 += 256) {
    int k = k0 + t;
    float v = (c < COUT) ? W2[(size_t)k * COUT + c] : 0.f;
    unsigned short hi = f2bf(v);
    unsigned short outv = hi;
    if (p) outv = f2bf(v - bfs(hi));
    W2b[((size_t)p * 48 + c) * CCAT + k] = outv;
  }
}

// ---------------- edge gather: 6-deep software-pipelined MLP, per-branch launch ----
// ef[e][br*256+c] = de_inv[e] * sum_{n in e} xq[br][n][c]

#define GDEEP 6

__global__ __launch_bounds__(256) void gatherx_k(
    const unsigned short* __restrict__ xq, const int* __restrict__ off_ec,
    const int* __restrict__ adj_e, const float* __restrict__ de_inv,
    unsigned short* __restrict__ ef, int br) {
  int e = blockIdx.x * 8 + (threadIdx.x >> 5);
  int lane = threadIdx.x & 31;
  const unsigned short* base = xq + (size_t)br * NNODES * CIN + lane * 8;
  int beg = off_ec[e * NCHN], end = off_ec[e * NCHN + NCHN];
  float a0 = 0, a1 = 0, a2 = 0, a3 = 0, a4 = 0, a5 = 0, a6 = 0, a7 = 0;
  int nA[GDEEP];
  #pragma unroll
  for (int u = 0; u < GDEEP; u++) nA[u] = (beg + u < end) ? adj_e[beg + u] : -1;
  for (int j = beg; j < end; j += GDEEP) {
    int nC[GDEEP];
    #pragma unroll
    for (int u = 0; u < GDEEP; u++) nC[u] = nA[u];
    int jn = j + GDEEP;
    #pragma unroll
    for (int u = 0; u < GDEEP; u++) nA[u] = (jn + u < end) ? adj_e[jn + u] : -1;
    #pragma unroll
    for (int u = 0; u < GDEEP; u++) {
      if (nC[u] >= 0) {
        uint4 v = *(const uint4*)(base + (size_t)nC[u] * CIN);
        a0 += bflo(v.x); a1 += bfhi(v.x);
        a2 += bflo(v.y); a3 += bfhi(v.y);
        a4 += bflo(v.z); a5 += bfhi(v.z);
        a6 += bflo(v.w); a7 += bfhi(v.w);
      }
    }
  }
  float sc = de_inv[e];
  uint4 o;
  o.x = packbf(a0 * sc, a1 * sc);
  o.y = packbf(a2 * sc, a3 * sc);
  o.z = packbf(a4 * sc, a5 * sc);
  o.w = packbf(a6 * sc, a7 * sc);
  *(uint4*)(ef + (size_t)e * CCAT + br * 256 + lane * 8) = o;
}

// ---------------- GEMM1 (MFMA bf16): G[br][e][256] = ef[e][br] @ W1[br] --------

__global__ __launch_bounds__(256) void gemm1_k(
    const unsigned short* __restrict__ ef,   // [E][1024] bf16 row-major
    const unsigned short* __restrict__ W1t,  // [4][256(n)][256(k)] bf16
    unsigned short* __restrict__ G) {        // [4][E][256] bf16 branch-major
  int rb = blockIdx.x, cb = blockIdx.y, br = blockIdx.z;
  int t = threadIdx.x;
  int w = t >> 6, l = t & 63;
  __shared__ unsigned short As[64 * 40];
  __shared__ unsigned short Bs[64 * 40];
  f32x4 acc[4] = {};
  int row0 = rb * 64;
  int srow = t >> 2, seg = t & 3;
  bool aok = (row0 + srow) < NEDGES;
  const unsigned short* ap = ef + (size_t)(row0 + srow) * CCAT + br * 256 + seg * 8;
  const unsigned short* bp = W1t + ((size_t)br * CIN + cb * 64 + srow) * CIN + seg * 8;
  int m = l & 15, q = l >> 4;
  for (int k0 = 0; k0 < CIN; k0 += 32) {
    uint4 av = {0, 0, 0, 0};
    if (aok) av = *(const uint4*)(ap + k0);
    uint4 bv = *(const uint4*)(bp + k0);
    *(uint4*)&As[srow * 40 + seg * 8] = av;
    *(uint4*)&Bs[srow * 40 + seg * 8] = bv;
    __syncthreads();
    bf16x8 a = *(bf16x8*)&As[(w * 16 + m) * 40 + q * 8];
    #pragma unroll
    for (int c = 0; c < 4; c++) {
      bf16x8 b = *(bf16x8*)&Bs[(c * 16 + m) * 40 + q * 8];
      acc[c] = __builtin_amdgcn_mfma_f32_16x16x32_bf16(a, b, acc[c], 0, 0, 0);
    }
    __syncthreads();
  }
  #pragma unroll
  for (int c = 0; c < 4; c++) {
    int f = cb * 64 + c * 16 + m;   // within-branch channel
    #pragma unroll
    for (int r = 0; r < 4; r++) {
      int row = row0 + w * 16 + q * 4 + r;
      if (row < NEDGES)
        G[((size_t)br * NEDGES + row) * 256 + f] = f2bf(acc[c][r]);
    }
  }
}

// ---------------- node scatter + bias + relu: 6-deep pipelined MLP -----

__global__ __launch_bounds__(256) void scatter_h_k(
    const unsigned short* __restrict__ G, const int* __restrict__ off_nc,
    const int* __restrict__ adj_n, const float* __restrict__ dv_is,
    const float* __restrict__ s1, const float* __restrict__ b1,
    unsigned short* __restrict__ hid) {   // [4][N][256] branch-major
  int br = blockIdx.y;
  int n = blockIdx.x * 8 + (threadIdx.x >> 5);
  int lane = threadIdx.x & 31;
  const unsigned short* base = G + (size_t)br * NEDGES * 256 + lane * 8;
  int beg = off_nc[n * NCHE], end = off_nc[n * NCHE + NCHE];
  float a0 = 0, a1 = 0, a2 = 0, a3 = 0, a4 = 0, a5 = 0, a6 = 0, a7 = 0;
  int nA[GDEEP];
  #pragma unroll
  for (int u = 0; u < GDEEP; u++) nA[u] = (beg + u < end) ? adj_n[beg + u] : -1;
  for (int j = beg; j < end; j += GDEEP) {
    int nC[GDEEP];
    #pragma unroll
    for (int u = 0; u < GDEEP; u++) nC[u] = nA[u];
    int jn = j + GDEEP;
    #pragma unroll
    for (int u = 0; u < GDEEP; u++) nA[u] = (jn + u < end) ? adj_n[jn + u] : -1;
    #pragma unroll
    for (int u = 0; u < GDEEP; u++) {
      if (nC[u] >= 0) {
        uint4 v = *(const uint4*)(base + (size_t)nC[u] * 256);
        a0 += bflo(v.x); a1 += bfhi(v.x);
        a2 += bflo(v.y); a3 += bfhi(v.y);
        a4 += bflo(v.z); a5 += bfhi(v.z);
        a6 += bflo(v.w); a7 += bfhi(v.w);
      }
    }
  }
  float wv = dv_is[n], sb = s1[n];
  const float* bp = b1 + br * 256 + lane * 8;
  float4 b0 = *(const float4*)bp;
  float4 b4 = *(const float4*)(bp + 4);
  float h0 = fmaxf(wv * a0 + sb * b0.x, 0.f);
  float h1 = fmaxf(wv * a1 + sb * b0.y, 0.f);
  float h2 = fmaxf(wv * a2 + sb * b0.z, 0.f);
  float h3 = fmaxf(wv * a3 + sb * b0.w, 0.f);
  float h4 = fmaxf(wv * a4 + sb * b4.x, 0.f);
  float h5 = fmaxf(wv * a5 + sb * b4.y, 0.f);
  float h6 = fmaxf(wv * a6 + sb * b4.z, 0.f);
  float h7 = fmaxf(wv * a7 + sb * b4.w, 0.f);
  uint4 o;
  o.x = packbf(h0, h1); o.y = packbf(h2, h3);
  o.z = packbf(h4, h5); o.w = packbf(h6, h7);
  *(uint4*)(hid + ((size_t)br * NNODES + n) * 256 + lane * 8) = o;
}

// ---- GEMM2 (MFMA bf16, no LDS): U[n][o] = hidden[n][:] @ W2 + b2, W2 2-term bf16 ----
// hidden branch-major [4][N][256]; W2b [2][48][1024]; 4 waves x 16 rows, 3 col-tiles.

__global__ __launch_bounds__(256) void gemm2_k(
    const unsigned short* __restrict__ H,    // [4][N][256] bf16 branch-major
    const unsigned short* __restrict__ W2b,  // [2][48][1024] bf16
    const float* __restrict__ b2, unsigned short* __restrict__ U) {
  int t = threadIdx.x;
  int w = t >> 6, l = t & 63;
  int m = l & 15, q = l >> 4;            // fragment row / k-segment
  int arow = blockIdx.x * 64 + w * 16 + m;
  int kseg = q * 8;
  bool aok = arow < NNODES;
  f32x4 acc[3] = {};
  for (int k0 = 0; k0 < CCAT; k0 += 32) {
    int k = k0 + kseg;
    int br = k >> 8, kin = k & 255;
    bf16x8 a = {};
    if (aok) a = *(const bf16x8*)(H + ((size_t)br * NNODES + arow) * 256 + kin);
    #pragma unroll
    for (int c = 0; c < 3; c++) {
      int col = c * 16 + m;
      bf16x8 bh = *(const bf16x8*)(W2b + (size_t)col * CCAT + k);
      bf16x8 bl = *(const bf16x8*)(W2b + (size_t)(48 + col) * CCAT + k);
      acc[c] = __builtin_amdgcn_mfma_f32_16x16x32_bf16(a, bh, acc[c], 0, 0, 0);
      acc[c] = __builtin_amdgcn_mfma_f32_16x16x32_bf16(a, bl, acc[c], 0, 0, 0);
    }
  }
  int rbase = blockIdx.x * 64 + w * 16 + q * 4;
  #pragma unroll
  for (int c = 0; c < 3; c++) {
    int col = c * 16 + m;
    if (col < COUT) {
      float bb = b2[col];
      #pragma unroll
      for (int r = 0; r < 4; r++) {
        int n = rbase + r;
        if (n < NNODES) U[(size_t)n * COUT + col] = f2bf(acc[c][r] + bb);
      }
    }
  }
}

// ---------------- final smooth (40 channels; U bf16, 4MB table) ----------------

__global__ __launch_bounds__(256) void gather_u_k(
    const unsigned short* __restrict__ U, const int* __restrict__ off_ec,
    const int* __restrict__ adj_e, const float* __restrict__ dv_is,
    const float* __restrict__ de_inv, float* __restrict__ ef2) {
  int e = blockIdx.x;
  int t = threadIdx.x;
  int w = t >> 6, lane = t & 63;
  __shared__ float red[4][COUT];
  float acc = 0.f;
  int beg = off_ec[e * NCHN], end = off_ec[e * NCHN + NCHN];
  if (lane < COUT) {
    for (int j = beg + w; j < end; j += 4) {
      int n = adj_e[j];
      acc += dv_is[n] * bfs(U[(size_t)n * COUT + lane]);
    }
    red[w][lane] = acc;
  }
  __syncthreads();
  if (t < COUT) {
    float s = red[0][t] + red[1][t] + red[2][t] + red[3][t];
    ef2[(size_t)e * COUT + t] = s * de_inv[e];
  }
}

__global__ __launch_bounds__(256) void scatter_out_k(
    const float* __restrict__ ef2, const int* __restrict__ off_nc,
    const int* __restrict__ adj_n, const float* __restrict__ dv_is,
    float* __restrict__ out) {
  int n = blockIdx.x;
  int t = threadIdx.x;
  int w = t >> 6, lane = t & 63;
  __shared__ float red[4][COUT];
  float acc = 0.f;
  int beg = off_nc[n * NCHE], end = off_nc[n * NCHE + NCHE];
  if (lane < COUT) {
    for (int j = beg + w; j < end; j += 4) {
      acc += ef2[(size_t)adj_n[j] * COUT + lane];
    }
    red[w][lane] = acc;
  }
  __syncthreads();
  if (t < COUT) {
    out[(size_t)n * COUT + t] = dv_is[n] * (red[0][t] + red[1][t] + red[2][t] + red[3][t]);
  }
}

// ---------------- launch ----------------

extern "C" void kernel_launch(void* const* d_in, const int* in_sizes, int n_in,
                              void* d_out, int out_size, void* d_ws, size_t ws_size,
                              hipStream_t stream) {
  const float* x  = (const float*)d_in[0];
  const float* W1 = (const float*)d_in[1];
  const float* b1 = (const float*)d_in[2];
  const float* W2 = (const float*)d_in[3];
  const float* b2 = (const float*)d_in[4];
  const int* ni   = (const int*)d_in[5];
  const int* ei   = (const int*)d_in[6];
  float* out = (float*)d_out;

  char* ws = (char*)d_ws;
  size_t o = 0;
  int* off_ec = (int*)(ws + o); o += (size_t)(NEDGES * NCHN + 1) * 4; o = (o + 255) & ~(size_t)255;
  int* off_nc = (int*)(ws + o); o += (size_t)(NNODES * NCHE + 1) * 4; o = (o + 255) & ~(size_t)255;
  float* de_inv = (float*)(ws + o); o += (size_t)NEDGES * 4;
  float* dv_is  = (float*)(ws + o); o += (size_t)NNODES * 4;
  float* t1     = (float*)(ws + o); o += (size_t)NEDGES * 4;
  float* s1     = (float*)(ws + o); o += (size_t)NNODES * 4; o = (o + 255) & ~(size_t)255;
  int* adj_e = (int*)(ws + o); o += (size_t)NNZT * 4;
  int* adj_n = (int*)(ws + o); o += (size_t)NNZT * 4; o = (o + 255) & ~(size_t)255;
  unsigned short* W1t = (unsigned short*)(ws + o); o += (size_t)4 * CIN * CIN * 2; o = (o + 255) & ~(size_t)255;
  unsigned short* W2b = (unsigned short*)(ws + o); o += (size_t)2 * 48 * CCAT * 2; o = (o + 255) & ~(size_t)255;
  // regionA: xq [4][N][256] bf16 branch-major; reused as hidden [4][N][256]
  unsigned short* xq     = (unsigned short*)(ws + o);
  unsigned short* hidden = xq;
  o += (size_t)NNODES * CCAT * 2; o = (o + 255) & ~(size_t)255;
  // regionB: ef [E][1024] bf16 row-major; later U [N][40] bf16 + ef2 [E][40] f32
  unsigned short* ef = (unsigned short*)(ws + o);
  unsigned short* u  = ef;
  float* ef2 = (float*)((char*)ef + (((size_t)NNODES * COUT * 2 + 255) & ~(size_t)255));
  o += (size_t)NEDGES * CCAT * 2; o = (o + 255) & ~(size_t)255;
  // regionC: G [4][E][256] bf16 branch-major. The CSR-build cnt/cur/blksum scratch is
  // overlaid at its start (build completes before gemm1_k writes G).
  unsigned short* g = (unsigned short*)(ws + o);
  o += (size_t)NEDGES * CCAT * 2;

  int* cnt_ec = (int*)g;                        // [E*NCHN]
  int* cur_ec = cnt_ec + (size_t)NEDGES * NCHN; // [E*NCHN]
  int* cnt_nc = cur_ec + (size_t)NEDGES * NCHN; // [N*NCHE]
  int* cur_nc = cnt_nc + (size_t)NNODES * NCHE; // [N*NCHE]
  int* blk_e  = cur_nc + (size_t)NNODES * NCHE; // [1024]
  int* blk_n  = blk_e + 1024;                   // [1024]

  const int LEN_E = NEDGES * NCHN;              // 260000
  const int LEN_N = NNODES * NCHE;              // 250000
  const int NBLK_E = (LEN_E + 1023) / 1024;     // 254
  const int NBLK_N = (LEN_N + 1023) / 1024;     // 245

  hipMemsetAsync(cnt_ec, 0,
                 ((size_t)LEN_E + (size_t)LEN_N) * 2 * sizeof(int),
                 stream);
  count_k<<<(NNZT + 255) / 256, 256, 0, stream>>>(ni, ei, cnt_ec, cnt_nc);
  scan_sum_k<<<NBLK_E, 256, 0, stream>>>(cnt_ec, blk_e, LEN_E);
  scan_top_k<<<1, 1024, 0, stream>>>(blk_e, NBLK_E);
  scan_apply_k<<<NBLK_E, 256, 0, stream>>>(cnt_ec, blk_e, off_ec, LEN_E);
  scan_sum_k<<<NBLK_N, 256, 0, stream>>>(cnt_nc, blk_n, LEN_N);
  scan_top_k<<<1, 1024, 0, stream>>>(blk_n, NBLK_N);
  scan_apply_k<<<NBLK_N, 256, 0, stream>>>(cnt_nc, blk_n, off_nc, LEN_N);
  fill_k<<<(NNZT + 255) / 256, 256, 0, stream>>>(ni, ei, off_ec, off_nc, cur_ec, cur_nc, adj_e, adj_n);
  deg_k<<<(NNODES + 255) / 256, 256, 0, stream>>>(off_ec, off_nc, de_inv, dv_is);
  castx_k<<<NNODES, 256, 0, stream>>>(x, dv_is, xq);
  castw1_k<<<dim3(CIN, 4), 256, 0, stream>>>(W1, W1t);
  castw2_k<<<dim3(48, 2), 256, 0, stream>>>(W2, W2b);
  t1_k<<<NEDGES, 64, 0, stream>>>(off_ec, adj_e, dv_is, de_inv, t1);
  s1_k<<<NNODES, 64, 0, stream>>>(off_nc, adj_n, t1, dv_is, s1);
  for (int br = 0; br < 4; br++)
    gatherx_k<<<NEDGES / 8, 256, 0, stream>>>(xq, off_ec, adj_e, de_inv, ef, br);
  gemm1_k<<<dim3((NEDGES + 63) / 64, 4, 4), 256, 0, stream>>>(ef, W1t, g);
  scatter_h_k<<<dim3(NNODES / 8, 4), 256, 0, stream>>>(g, off_nc, adj_n, dv_is, s1, b1, hidden);
  gemm2_k<<<(NNODES + 63) / 64, 256, 0, stream>>>(hidden, W2b, b2, u);
  gather_u_k<<<NEDGES, 256, 0, stream>>>(u, off_ec, adj_e, dv_is, de_inv, ef2);
  scatter_out_k<<<NNODES, 256, 0, stream>>>(ef2, off_nc, adj_n, dv_is, out);
}

// Round 8
// 1550.046 us; speedup vs baseline: 1.1894x; 1.0605x over previous
//
#include <hip/hip_runtime.h>
#include <cstdint>
#include <cstddef>

#define NNODES 50000
#define NEDGES 20000
#define NNZT   1600000
#define CCAT   1024   // 4*256 concat features
#define CIN    256
#define COUT   40

// chunk-grouped adjacency: neighbor lists sorted by 4096-wide chunk of the gathered
// array (passive cross-block temporal locality). Sparse passes sweep (half, branch)
// phases serialized by dispatch order; hot slab per phase: gatherx 12.8MB, scatter 5.12MB.
#define NCHN 13   // ceil(50000/4096) node chunks
#define NCHE 5    // ceil(20000/4096) edge chunks

typedef __attribute__((ext_vector_type(8))) short bf16x8;
typedef __attribute__((ext_vector_type(4))) float f32x4;

__device__ inline float bflo(unsigned u) { return __uint_as_float(u << 16); }
__device__ inline float bfhi(unsigned u) { return __uint_as_float(u & 0xffff0000u); }
__device__ inline float bfs(unsigned short u) { return __uint_as_float((unsigned)u << 16); }
__device__ inline unsigned short f2bf(float f) {
  unsigned u = __float_as_uint(f);
  u += 0x7fff + ((u >> 16) & 1);
  return (unsigned short)(u >> 16);
}
__device__ inline unsigned packbf(float a, float b) {
  return (unsigned)f2bf(a) | ((unsigned)f2bf(b) << 16);
}

// ---------------- CSR build (chunk-grouped) ----------------

__global__ void count_k(const int* __restrict__ ni, const int* __restrict__ ei,
                        int* __restrict__ cnt_ec, int* __restrict__ cnt_nc) {
  int i = blockIdx.x * 256 + threadIdx.x;
  if (i < NNZT) {
    int n = ni[i], e = ei[i];
    atomicAdd(&cnt_ec[e * NCHN + (n >> 12)], 1);
    atomicAdd(&cnt_nc[n * NCHE + (e >> 12)], 1);
  }
}

// ---- hierarchical exclusive scan (3 kernels; len up to 1024*1024) ----

__global__ __launch_bounds__(256) void scan_sum_k(
    const int* __restrict__ cnt, int* __restrict__ blksum, int len) {
  int b = blockIdx.x;
  int i0 = b * 1024 + threadIdx.x * 4;
  int s = 0;
  #pragma unroll
  for (int j = 0; j < 4; j++) { int i = i0 + j; if (i < len) s += cnt[i]; }
  __shared__ int sh[4];
  for (int d = 32; d > 0; d >>= 1) s += __shfl_down(s, d);
  if ((threadIdx.x & 63) == 0) sh[threadIdx.x >> 6] = s;
  __syncthreads();
  if (threadIdx.x == 0) blksum[b] = sh[0] + sh[1] + sh[2] + sh[3];
}

__global__ __launch_bounds__(1024) void scan_top_k(int* __restrict__ blksum, int nblk) {
  // in-place exclusive scan of blksum[0..nblk), nblk <= 1024
  __shared__ int sh[1024];
  int t = threadIdx.x;
  int v = (t < nblk) ? blksum[t] : 0;
  sh[t] = v;
  __syncthreads();
  for (int d = 1; d < 1024; d <<= 1) {
    int u = (t >= d) ? sh[t - d] : 0;
    __syncthreads();
    sh[t] += u;
    __syncthreads();
  }
  if (t < nblk) blksum[t] = sh[t] - v;
}

__global__ __launch_bounds__(256) void scan_apply_k(
    const int* __restrict__ cnt, const int* __restrict__ blksum,
    int* __restrict__ off, int len) {
  int b = blockIdx.x;
  int t = threadIdx.x;
  int i0 = b * 1024 + t * 4;
  int v[4];
  int s = 0;
  #pragma unroll
  for (int j = 0; j < 4; j++) { int i = i0 + j; v[j] = (i < len) ? cnt[i] : 0; s += v[j]; }
  __shared__ int sh[256];
  sh[t] = s;
  __syncthreads();
  for (int d = 1; d < 256; d <<= 1) {
    int u = (t >= d) ? sh[t - d] : 0;
    __syncthreads();
    sh[t] += u;
    __syncthreads();
  }
  int run = blksum[b] + sh[t] - s;   // exclusive prefix at this thread's first elem
  #pragma unroll
  for (int j = 0; j < 4; j++) {
    int i = i0 + j;
    if (i < len) off[i] = run;
    run += v[j];
  }
  if (b == gridDim.x - 1 && t == 255) off[len] = run;  // grand total
}

__global__ void fill_k(const int* __restrict__ ni, const int* __restrict__ ei,
                       const int* __restrict__ off_ec, const int* __restrict__ off_nc,
                       int* __restrict__ cur_ec, int* __restrict__ cur_nc,
                       int* __restrict__ adj_e, int* __restrict__ adj_n) {
  int i = blockIdx.x * 256 + threadIdx.x;
  if (i < NNZT) {
    int e = ei[i], n = ni[i];
    int ce = e * NCHN + (n >> 12);
    int p = atomicAdd(&cur_ec[ce], 1);
    adj_e[off_ec[ce] + p] = n;
    int cn = n * NCHE + (e >> 12);
    int q = atomicAdd(&cur_nc[cn], 1);
    adj_n[off_nc[cn] + q] = e;
  }
}

__global__ void deg_k(const int* __restrict__ off_ec, const int* __restrict__ off_nc,
                      float* __restrict__ de_inv, float* __restrict__ dv_is) {
  int i = blockIdx.x * 256 + threadIdx.x;
  if (i < NNODES) {
    int d = off_nc[(i + 1) * NCHE] - off_nc[i * NCHE];
    dv_is[i] = (d > 0) ? rsqrtf((float)d) : 0.f;
  }
  if (i < NEDGES) {
    int d = off_ec[(i + 1) * NCHN] - off_ec[i * NCHN];
    de_inv[i] = (d > 0) ? (1.f / (float)d) : 0.f;
  }
}

// ---------------- s1 = S * ones (bias-through-smooth) ----------------

__global__ void t1_k(const int* __restrict__ off_ec, const int* __restrict__ adj_e,
                     const float* __restrict__ dv_is, const float* __restrict__ de_inv,
                     float* __restrict__ t1) {
  int e = blockIdx.x; int lane = threadIdx.x;
  int beg = off_ec[e * NCHN], end = off_ec[e * NCHN + NCHN];
  float s = 0.f;
  for (int j = beg + lane; j < end; j += 64) s += dv_is[adj_e[j]];
  for (int d = 32; d > 0; d >>= 1) s += __shfl_down(s, d);
  if (lane == 0) t1[e] = s * de_inv[e];
}

__global__ void s1_k(const int* __restrict__ off_nc, const int* __restrict__ adj_n,
                     const float* __restrict__ t1, const float* __restrict__ dv_is,
                     float* __restrict__ s1) {
  int n = blockIdx.x; int lane = threadIdx.x;
  int beg = off_nc[n * NCHE], end = off_nc[n * NCHE + NCHE];
  float s = 0.f;
  for (int j = beg + lane; j < end; j += 64) s += t1[adj_n[j]];
  for (int d = 32; d > 0; d >>= 1) s += __shfl_down(s, d);
  if (lane == 0) s1[n] = s * dv_is[n];
}

// ---------------- castx: xq[br][n][256] = bf16(dv_is[n]*x[br][n][:]) ----------------

__global__ __launch_bounds__(256) void castx_k(
    const float* __restrict__ x, const float* __restrict__ dv_is,
    unsigned short* __restrict__ xq) {
  int n = blockIdx.x;
  int t = threadIdx.x;
  int br = t >> 6, c4 = (t & 63) * 4;
  float dv = dv_is[n];
  float4 v = *(const float4*)(x + ((size_t)br * NNODES + n) * CIN + c4);
  ushort4 o;
  o.x = f2bf(v.x * dv); o.y = f2bf(v.y * dv);
  o.z = f2bf(v.z * dv); o.w = f2bf(v.w * dv);
  *(ushort4*)(xq + ((size_t)br * NNODES + n) * CIN + c4) = o;
}

// W1t[br][n][k] = bf16(W1[br][k][n])
__global__ __launch_bounds__(256) void castw1_k(
    const float* __restrict__ W1, unsigned short* __restrict__ W1t) {
  int n = blockIdx.x, br = blockIdx.y, t = threadIdx.x;
  float v = W1[((size_t)br * CIN + t) * CIN + n];
  W1t[((size_t)br * CIN + n) * CIN + t] = f2bf(v);
}

// W2b[p][c][k]: 2-term bf16 split of W2[k][c] (p=0 hi, p=1 residual), cols padded to 48
__global__ __launch_bounds__(256) void castw2_k(
    const float* __restrict__ W2, unsigned short* __restrict__ W2b) {
  int c = blockIdx.x;      // 0..47
  int p = blockIdx.y;      // 0..1
  int t = threadIdx.x;
  for (int k0 = 0; k0 < CCAT; k0 += 256) {
    int k = k0 + t;
    float v = (c < COUT) ? W2[(size_t)k * COUT + c] : 0.f;
    unsigned short hi = f2bf(v);
    unsigned short outv = hi;
    if (p) outv = f2bf(v - bfs(hi));
    W2b[((size_t)p * 48 + c) * CCAT + k] = outv;
  }
}

// ----- edge gather: 6-deep pipelined MLP, 128-ch half rows, (half,branch) phases -----
// ef[e][br*256+half*128+c] = de_inv[e] * sum_{n in e} xq[br][n][half*128+c]

#define GDEEP 6

__global__ __launch_bounds__(256) void gatherx_k(
    const unsigned short* __restrict__ xq, const int* __restrict__ off_ec,
    const int* __restrict__ adj_e, const float* __restrict__ de_inv,
    unsigned short* __restrict__ ef) {
  int half = blockIdx.y, br = blockIdx.z;
  int e = blockIdx.x * 16 + (threadIdx.x >> 4);
  int lane = threadIdx.x & 15;
  const unsigned short* base = xq + (size_t)br * NNODES * CIN + half * 128 + lane * 8;
  int beg = off_ec[e * NCHN], end = off_ec[e * NCHN + NCHN];
  float a0 = 0, a1 = 0, a2 = 0, a3 = 0, a4 = 0, a5 = 0, a6 = 0, a7 = 0;
  int nA[GDEEP];
  #pragma unroll
  for (int u = 0; u < GDEEP; u++) nA[u] = (beg + u < end) ? adj_e[beg + u] : -1;
  for (int j = beg; j < end; j += GDEEP) {
    int nC[GDEEP];
    #pragma unroll
    for (int u = 0; u < GDEEP; u++) nC[u] = nA[u];
    int jn = j + GDEEP;
    #pragma unroll
    for (int u = 0; u < GDEEP; u++) nA[u] = (jn + u < end) ? adj_e[jn + u] : -1;
    #pragma unroll
    for (int u = 0; u < GDEEP; u++) {
      if (nC[u] >= 0) {
        uint4 v = *(const uint4*)(base + (size_t)nC[u] * CIN);
        a0 += bflo(v.x); a1 += bfhi(v.x);
        a2 += bflo(v.y); a3 += bfhi(v.y);
        a4 += bflo(v.z); a5 += bfhi(v.z);
        a6 += bflo(v.w); a7 += bfhi(v.w);
      }
    }
  }
  float sc = de_inv[e];
  uint4 o;
  o.x = packbf(a0 * sc, a1 * sc);
  o.y = packbf(a2 * sc, a3 * sc);
  o.z = packbf(a4 * sc, a5 * sc);
  o.w = packbf(a6 * sc, a7 * sc);
  *(uint4*)(ef + (size_t)e * CCAT + br * 256 + half * 128 + lane * 8) = o;
}

// ---------------- GEMM1 (MFMA bf16): G[br][e][256] = ef[e][br] @ W1[br] --------

__global__ __launch_bounds__(256) void gemm1_k(
    const unsigned short* __restrict__ ef,   // [E][1024] bf16 row-major
    const unsigned short* __restrict__ W1t,  // [4][256(n)][256(k)] bf16
    unsigned short* __restrict__ G) {        // [4][E][256] bf16 branch-major
  int rb = blockIdx.x, cb = blockIdx.y, br = blockIdx.z;
  int t = threadIdx.x;
  int w = t >> 6, l = t & 63;
  __shared__ unsigned short As[64 * 40];
  __shared__ unsigned short Bs[64 * 40];
  f32x4 acc[4] = {};
  int row0 = rb * 64;
  int srow = t >> 2, seg = t & 3;
  bool aok = (row0 + srow) < NEDGES;
  const unsigned short* ap = ef + (size_t)(row0 + srow) * CCAT + br * 256 + seg * 8;
  const unsigned short* bp = W1t + ((size_t)br * CIN + cb * 64 + srow) * CIN + seg * 8;
  int m = l & 15, q = l >> 4;
  for (int k0 = 0; k0 < CIN; k0 += 32) {
    uint4 av = {0, 0, 0, 0};
    if (aok) av = *(const uint4*)(ap + k0);
    uint4 bv = *(const uint4*)(bp + k0);
    *(uint4*)&As[srow * 40 + seg * 8] = av;
    *(uint4*)&Bs[srow * 40 + seg * 8] = bv;
    __syncthreads();
    bf16x8 a = *(bf16x8*)&As[(w * 16 + m) * 40 + q * 8];
    #pragma unroll
    for (int c = 0; c < 4; c++) {
      bf16x8 b = *(bf16x8*)&Bs[(c * 16 + m) * 40 + q * 8];
      acc[c] = __builtin_amdgcn_mfma_f32_16x16x32_bf16(a, b, acc[c], 0, 0, 0);
    }
    __syncthreads();
  }
  #pragma unroll
  for (int c = 0; c < 4; c++) {
    int f = cb * 64 + c * 16 + m;   // within-branch channel
    #pragma unroll
    for (int r = 0; r < 4; r++) {
      int row = row0 + w * 16 + q * 4 + r;
      if (row < NEDGES)
        G[((size_t)br * NEDGES + row) * 256 + f] = f2bf(acc[c][r]);
    }
  }
}

// -- node scatter + bias + relu: 6-deep pipelined MLP, 128-ch half rows, phased --

__global__ __launch_bounds__(256) void scatter_h_k(
    const unsigned short* __restrict__ G, const int* __restrict__ off_nc,
    const int* __restrict__ adj_n, const float* __restrict__ dv_is,
    const float* __restrict__ s1, const float* __restrict__ b1,
    unsigned short* __restrict__ hid) {   // [4][N][256] branch-major
  int half = blockIdx.y, br = blockIdx.z;
  int n = blockIdx.x * 16 + (threadIdx.x >> 4);
  int lane = threadIdx.x & 15;
  const unsigned short* base = G + (size_t)br * NEDGES * 256 + half * 128 + lane * 8;
  int beg = off_nc[n * NCHE], end = off_nc[n * NCHE + NCHE];
  float a0 = 0, a1 = 0, a2 = 0, a3 = 0, a4 = 0, a5 = 0, a6 = 0, a7 = 0;
  int nA[GDEEP];
  #pragma unroll
  for (int u = 0; u < GDEEP; u++) nA[u] = (beg + u < end) ? adj_n[beg + u] : -1;
  for (int j = beg; j < end; j += GDEEP) {
    int nC[GDEEP];
    #pragma unroll
    for (int u = 0; u < GDEEP; u++) nC[u] = nA[u];
    int jn = j + GDEEP;
    #pragma unroll
    for (int u = 0; u < GDEEP; u++) nA[u] = (jn + u < end) ? adj_n[jn + u] : -1;
    #pragma unroll
    for (int u = 0; u < GDEEP; u++) {
      if (nC[u] >= 0) {
        uint4 v = *(const uint4*)(base + (size_t)nC[u] * 256);
        a0 += bflo(v.x); a1 += bfhi(v.x);
        a2 += bflo(v.y); a3 += bfhi(v.y);
        a4 += bflo(v.z); a5 += bfhi(v.z);
        a6 += bflo(v.w); a7 += bfhi(v.w);
      }
    }
  }
  float wv = dv_is[n], sb = s1[n];
  const float* bp = b1 + br * 256 + half * 128 + lane * 8;
  float4 b0 = *(const float4*)bp;
  float4 b4 = *(const float4*)(bp + 4);
  float h0 = fmaxf(wv * a0 + sb * b0.x, 0.f);
  float h1 = fmaxf(wv * a1 + sb * b0.y, 0.f);
  float h2 = fmaxf(wv * a2 + sb * b0.z, 0.f);
  float h3 = fmaxf(wv * a3 + sb * b0.w, 0.f);
  float h4 = fmaxf(wv * a4 + sb * b4.x, 0.f);
  float h5 = fmaxf(wv * a5 + sb * b4.y, 0.f);
  float h6 = fmaxf(wv * a6 + sb * b4.z, 0.f);
  float h7 = fmaxf(wv * a7 + sb * b4.w, 0.f);
  uint4 o;
  o.x = packbf(h0, h1); o.y = packbf(h2, h3);
  o.z = packbf(h4, h5); o.w = packbf(h6, h7);
  *(uint4*)(hid + ((size_t)br * NNODES + n) * 256 + half * 128 + lane * 8) = o;
}

// ---- GEMM2 (MFMA bf16, no LDS): U[n][o] = hidden[n][:] @ W2 + b2, W2 2-term bf16 ----
// hidden branch-major [4][N][256]; W2b [2][48][1024]; 4 waves x 16 rows, 3 col-tiles.

__global__ __launch_bounds__(256) void gemm2_k(
    const unsigned short* __restrict__ H,    // [4][N][256] bf16 branch-major
    const unsigned short* __restrict__ W2b,  // [2][48][1024] bf16
    const float* __restrict__ b2, unsigned short* __restrict__ U) {
  int t = threadIdx.x;
  int w = t >> 6, l = t & 63;
  int m = l & 15, q = l >> 4;            // fragment row / k-segment
  int arow = blockIdx.x * 64 + w * 16 + m;
  int kseg = q * 8;
  bool aok = arow < NNODES;
  f32x4 acc[3] = {};
  for (int k0 = 0; k0 < CCAT; k0 += 32) {
    int k = k0 + kseg;
    int br = k >> 8, kin = k & 255;
    bf16x8 a = {};
    if (aok) a = *(const bf16x8*)(H + ((size_t)br * NNODES + arow) * 256 + kin);
    #pragma unroll
    for (int c = 0; c < 3; c++) {
      int col = c * 16 + m;
      bf16x8 bh = *(const bf16x8*)(W2b + (size_t)col * CCAT + k);
      bf16x8 bl = *(const bf16x8*)(W2b + (size_t)(48 + col) * CCAT + k);
      acc[c] = __builtin_amdgcn_mfma_f32_16x16x32_bf16(a, bh, acc[c], 0, 0, 0);
      acc[c] = __builtin_amdgcn_mfma_f32_16x16x32_bf16(a, bl, acc[c], 0, 0, 0);
    }
  }
  int rbase = blockIdx.x * 64 + w * 16 + q * 4;
  #pragma unroll
  for (int c = 0; c < 3; c++) {
    int col = c * 16 + m;
    if (col < COUT) {
      float bb = b2[col];
      #pragma unroll
      for (int r = 0; r < 4; r++) {
        int n = rbase + r;
        if (n < NNODES) U[(size_t)n * COUT + col] = f2bf(acc[c][r] + bb);
      }
    }
  }
}

// ---------------- final smooth (40 channels; U bf16, 4MB table) ----------------

__global__ __launch_bounds__(256) void gather_u_k(
    const unsigned short* __restrict__ U, const int* __restrict__ off_ec,
    const int* __restrict__ adj_e, const float* __restrict__ dv_is,
    const float* __restrict__ de_inv, float* __restrict__ ef2) {
  int e = blockIdx.x;
  int t = threadIdx.x;
  int w = t >> 6, lane = t & 63;
  __shared__ float red[4][COUT];
  float acc = 0.f;
  int beg = off_ec[e * NCHN], end = off_ec[e * NCHN + NCHN];
  if (lane < COUT) {
    for (int j = beg + w; j < end; j += 4) {
      int n = adj_e[j];
      acc += dv_is[n] * bfs(U[(size_t)n * COUT + lane]);
    }
    red[w][lane] = acc;
  }
  __syncthreads();
  if (t < COUT) {
    float s = red[0][t] + red[1][t] + red[2][t] + red[3][t];
    ef2[(size_t)e * COUT + t] = s * de_inv[e];
  }
}

__global__ __launch_bounds__(256) void scatter_out_k(
    const float* __restrict__ ef2, const int* __restrict__ off_nc,
    const int* __restrict__ adj_n, const float* __restrict__ dv_is,
    float* __restrict__ out) {
  int n = blockIdx.x;
  int t = threadIdx.x;
  int w = t >> 6, lane = t & 63;
  __shared__ float red[4][COUT];
  float acc = 0.f;
  int beg = off_nc[n * NCHE], end = off_nc[n * NCHE + NCHE];
  if (lane < COUT) {
    for (int j = beg + w; j < end; j += 4) {
      acc += ef2[(size_t)adj_n[j] * COUT + lane];
    }
    red[w][lane] = acc;
  }
  __syncthreads();
  if (t < COUT) {
    out[(size_t)n * COUT + t] = dv_is[n] * (red[0][t] + red[1][t] + red[2][t] + red[3][t]);
  }
}

// ---------------- launch ----------------

extern "C" void kernel_launch(void* const* d_in, const int* in_sizes, int n_in,
                              void* d_out, int out_size, void* d_ws, size_t ws_size,
                              hipStream_t stream) {
  const float* x  = (const float*)d_in[0];
  const float* W1 = (const float*)d_in[1];
  const float* b1 = (const float*)d_in[2];
  const float* W2 = (const float*)d_in[3];
  const float* b2 = (const float*)d_in[4];
  const int* ni   = (const int*)d_in[5];
  const int* ei   = (const int*)d_in[6];
  float* out = (float*)d_out;

  char* ws = (char*)d_ws;
  size_t o = 0;
  int* off_ec = (int*)(ws + o); o += (size_t)(NEDGES * NCHN + 1) * 4; o = (o + 255) & ~(size_t)255;
  int* off_nc = (int*)(ws + o); o += (size_t)(NNODES * NCHE + 1) * 4; o = (o + 255) & ~(size_t)255;
  float* de_inv = (float*)(ws + o); o += (size_t)NEDGES * 4;
  float* dv_is  = (float*)(ws + o); o += (size_t)NNODES * 4;
  float* t1     = (float*)(ws + o); o += (size_t)NEDGES * 4;
  float* s1     = (float*)(ws + o); o += (size_t)NNODES * 4; o = (o + 255) & ~(size_t)255;
  int* adj_e = (int*)(ws + o); o += (size_t)NNZT * 4;
  int* adj_n = (int*)(ws + o); o += (size_t)NNZT * 4; o = (o + 255) & ~(size_t)255;
  unsigned short* W1t = (unsigned short*)(ws + o); o += (size_t)4 * CIN * CIN * 2; o = (o + 255) & ~(size_t)255;
  unsigned short* W2b = (unsigned short*)(ws + o); o += (size_t)2 * 48 * CCAT * 2; o = (o + 255) & ~(size_t)255;
  // regionA: xq [4][N][256] bf16 branch-major; reused as hidden [4][N][256]
  unsigned short* xq     = (unsigned short*)(ws + o);
  unsigned short* hidden = xq;
  o += (size_t)NNODES * CCAT * 2; o = (o + 255) & ~(size_t)255;
  // regionB: ef [E][1024] bf16 row-major; later U [N][40] bf16 + ef2 [E][40] f32
  unsigned short* ef = (unsigned short*)(ws + o);
  unsigned short* u  = ef;
  float* ef2 = (float*)((char*)ef + (((size_t)NNODES * COUT * 2 + 255) & ~(size_t)255));
  o += (size_t)NEDGES * CCAT * 2; o = (o + 255) & ~(size_t)255;
  // regionC: G [4][E][256] bf16 branch-major. The CSR-build cnt/cur/blksum scratch is
  // overlaid at its start (build completes before gemm1_k writes G).
  unsigned short* g = (unsigned short*)(ws + o);
  o += (size_t)NEDGES * CCAT * 2;

  int* cnt_ec = (int*)g;                        // [E*NCHN]
  int* cur_ec = cnt_ec + (size_t)NEDGES * NCHN; // [E*NCHN]
  int* cnt_nc = cur_ec + (size_t)NEDGES * NCHN; // [N*NCHE]
  int* cur_nc = cnt_nc + (size_t)NNODES * NCHE; // [N*NCHE]
  int* blk_e  = cur_nc + (size_t)NNODES * NCHE; // [1024]
  int* blk_n  = blk_e + 1024;                   // [1024]

  const int LEN_E = NEDGES * NCHN;              // 260000
  const int LEN_N = NNODES * NCHE;              // 250000
  const int NBLK_E = (LEN_E + 1023) / 1024;     // 254
  const int NBLK_N = (LEN_N + 1023) / 1024;     // 245

  hipMemsetAsync(cnt_ec, 0,
                 ((size_t)LEN_E + (size_t)LEN_N) * 2 * sizeof(int),
                 stream);
  count_k<<<(NNZT + 255) / 256, 256, 0, stream>>>(ni, ei, cnt_ec, cnt_nc);
  scan_sum_k<<<NBLK_E, 256, 0, stream>>>(cnt_ec, blk_e, LEN_E);
  scan_top_k<<<1, 1024, 0, stream>>>(blk_e, NBLK_E);
  scan_apply_k<<<NBLK_E, 256, 0, stream>>>(cnt_ec, blk_e, off_ec, LEN_E);
  scan_sum_k<<<NBLK_N, 256, 0, stream>>>(cnt_nc, blk_n, LEN_N);
  scan_top_k<<<1, 1024, 0, stream>>>(blk_n, NBLK_N);
  scan_apply_k<<<NBLK_N, 256, 0, stream>>>(cnt_nc, blk_n, off_nc, LEN_N);
  fill_k<<<(NNZT + 255) / 256, 256, 0, stream>>>(ni, ei, off_ec, off_nc, cur_ec, cur_nc, adj_e, adj_n);
  deg_k<<<(NNODES + 255) / 256, 256, 0, stream>>>(off_ec, off_nc, de_inv, dv_is);
  castx_k<<<NNODES, 256, 0, stream>>>(x, dv_is, xq);
  castw1_k<<<dim3(CIN, 4), 256, 0, stream>>>(W1, W1t);
  castw2_k<<<dim3(48, 2), 256, 0, stream>>>(W2, W2b);
  t1_k<<<NEDGES, 64, 0, stream>>>(off_ec, adj_e, dv_is, de_inv, t1);
  s1_k<<<NNODES, 64, 0, stream>>>(off_nc, adj_n, t1, dv_is, s1);
  gatherx_k<<<dim3(NEDGES / 16, 2, 4), 256, 0, stream>>>(xq, off_ec, adj_e, de_inv, ef);
  gemm1_k<<<dim3((NEDGES + 63) / 64, 4, 4), 256, 0, stream>>>(ef, W1t, g);
  scatter_h_k<<<dim3(NNODES / 16, 2, 4), 256, 0, stream>>>(g, off_nc, adj_n, dv_is, s1, b1, hidden);
  gemm2_k<<<(NNODES + 63) / 64, 256, 0, stream>>>(hidden, W2b, b2, u);
  gather_u_k<<<NEDGES, 256, 0, stream>>>(u, off_ec, adj_e, dv_is, de_inv, ef2);
  scatter_out_k<<<NNODES, 256, 0, stream>>>(ef2, off_nc, adj_n, dv_is, out);
}